// Round 2
// baseline (202.457 us; speedup 1.0000x reference)
//
#include <hip/hip_runtime.h>
#include <hip/hip_bf16.h>
#include <cstdint>

// Problem constants (B=16, N=4096, D_IN=D_OUT=64)
#define NB   16
#define NN   4096
#define ND   64
#define NJ   1024   // NB*ND columns of the big GEMM

typedef __attribute__((ext_vector_type(8))) short  short8;  // 8 bf16 = 4 VGPRs
typedef __attribute__((ext_vector_type(4))) float  f32x4;

__device__ __forceinline__ unsigned short f2bf(float f) {
  union { float f; unsigned int u; } v; v.f = f;
  unsigned int u = v.u;
  unsigned int r = u + 0x7FFFu + ((u >> 16) & 1u);  // round-to-nearest-even
  return (unsigned short)(r >> 16);
}
__device__ __forceinline__ float bf2f(unsigned short h) {
  union { unsigned int u; float f; } v; v.u = ((unsigned int)h) << 16; return v.f;
}

// ---------------- K1: merged prep = {A fp32->bf16 convert} + {Yt = (Z W)^T} --------
// bx < 8192: convert path (8 elems/thread, fully vectorized).
// bx >= 8192: zw path (1024 blocks). Block 8192 also zeroes the 128 split-K counters
// (cannot rely on ws fill pattern between iterations).
__global__ void k_prep(const float* __restrict__ A, const float* __restrict__ Z,
                       const float* __restrict__ W, unsigned short* __restrict__ Ab,
                       unsigned short* __restrict__ Yt, int* __restrict__ cnt) {
  int bx = blockIdx.x;
  if (bx < 8192) {
    int idx = bx * 256 + threadIdx.x;                // 2,097,152 threads exactly
    const float4* p = (const float4*)A + (size_t)idx * 2;
    float4 a = p[0], b = p[1];
    unsigned int w0 = (unsigned int)f2bf(a.x) | ((unsigned int)f2bf(a.y) << 16);
    unsigned int w1 = (unsigned int)f2bf(a.z) | ((unsigned int)f2bf(a.w) << 16);
    unsigned int w2 = (unsigned int)f2bf(b.x) | ((unsigned int)f2bf(b.y) << 16);
    unsigned int w3 = (unsigned int)f2bf(b.z) | ((unsigned int)f2bf(b.w) << 16);
    uint4 o; o.x = w0; o.y = w1; o.z = w2; o.w = w3;
    ((uint4*)Ab)[idx] = o;                           // 16B store
  } else {
    int bz = bx - 8192;                              // [0,1024)
    if (bz == 0 && threadIdx.x < 128) cnt[threadIdx.x] = 0;
    int lane = threadIdx.x & 63;
    int e0 = __builtin_amdgcn_readfirstlane((threadIdx.x >> 6) << 4);
    int b  = bz >> 6;                  // [0,16)
    int m0 = (bz & 63) << 6;           // [0,4096) step 64
    int m  = m0 + lane;
    const float* zr = Z + ((size_t)b * NN + m) * ND;
    float z[64];
#pragma unroll
    for (int g = 0; g < 16; ++g) *(float4*)&z[g * 4] = ((const float4*)zr)[g];
    float acc[16];
#pragma unroll
    for (int i = 0; i < 16; ++i) acc[i] = 0.f;
#pragma unroll
    for (int d = 0; d < 64; ++d) {
      float zd = z[d];
#pragma unroll
      for (int i = 0; i < 16; ++i) acc[i] += zd * W[d * 64 + e0 + i];  // uniform -> SMEM
    }
#pragma unroll
    for (int i = 0; i < 16; ++i)
      Yt[(size_t)(b * 64 + e0 + i) * NN + m] = f2bf(acc[i]);
  }
}

// ---------------- K2: 256x128-tile 8-phase GEMM, split-K x2, fused tail-reduce ------
// Grid 256 = 16m x 8j x 2kc, 1 block/CU, 512 thr = 8 waves (2M x 4N), per-wave 128x32.
// K/block = 2048 -> 32 K-tiles of BK=64 (2x deeper than before: ramp/epi amortized).
// LDS 128 KiB exactly: A triple-buffered 3x[256][64] shorts (2-K-tile prefetch
// distance ~4 phases > HBM latency, so steady vmcnt(6) is free), B double-buffered
// 2x[128][64]. Chunk-XOR swizzle identical to verified kernel (0 conflicts measured).
// Per K-tile: 2 phases x {ds_read, stage-issue, barrier, lgkm0, setprio, 16 MFMA,
// setprio, barrier}; one counted vmcnt per K-tile, never 0 in steady state.
// Tail: both kc-partners store bf16 partials; fence+atomic counter; the SECOND
// finisher (same XCD by swizzle; fences make it correct regardless) reads partner's
// partial, adds its own fp32 acc, writes fp32 out directly. k_reduce is gone.
__device__ __forceinline__ void gl2lds16(const unsigned short* g, unsigned short* l) {
  __builtin_amdgcn_global_load_lds(
      (const __attribute__((address_space(1))) unsigned int*)g,
      (__attribute__((address_space(3))) unsigned int*)l, 16, 0, 0);
}

#define STAGE_A(TT, BUF) { \
  const unsigned short* g_ = Ag + (TT) * 64; unsigned short* l_ = lds + (BUF) * 16384; \
  gl2lds16(g_ + srcA[0], l_ + dstA[0]); gl2lds16(g_ + srcA[1], l_ + dstA[1]); \
  gl2lds16(g_ + srcA[2], l_ + dstA[2]); gl2lds16(g_ + srcA[3], l_ + dstA[3]); }

#define STAGE_B(TT, BUF) { \
  const unsigned short* g_ = Bg + (TT) * 64; unsigned short* l_ = lds + 49152 + (BUF) * 8192; \
  gl2lds16(g_ + srcB[0], l_ + dstB[0]); gl2lds16(g_ + srcB[1], l_ + dstB[1]); }

#define PHASE_MFMA(I0) \
  __builtin_amdgcn_s_barrier(); \
  asm volatile("s_waitcnt lgkmcnt(0)" ::: "memory"); \
  __builtin_amdgcn_s_setprio(1); \
  _Pragma("unroll") \
  for (int i = 0; i < 4; ++i) { \
    _Pragma("unroll") \
    for (int j = 0; j < 2; ++j) { \
      acc[(I0) + i][j] = __builtin_amdgcn_mfma_f32_16x16x32_bf16(afr[i][0], bfr[j][0], acc[(I0) + i][j], 0, 0, 0); \
      acc[(I0) + i][j] = __builtin_amdgcn_mfma_f32_16x16x32_bf16(afr[i][1], bfr[j][1], acc[(I0) + i][j], 0, 0, 0); \
    } \
  } \
  __builtin_amdgcn_s_setprio(0); \
  __builtin_amdgcn_s_barrier();

__launch_bounds__(512, 2)  // 8 waves, 1 block/CU (128 KiB LDS), VGPR cap 256
__global__ void k_gemm(const unsigned short* __restrict__ Ab,
                       const unsigned short* __restrict__ Yt,
                       unsigned short* __restrict__ Pb,
                       float* __restrict__ out, int* __restrict__ cnt) {
  __shared__ unsigned short lds[65536];  // 128 KiB: A 3x16384 @0, B 2x8192 @49152
  const int tid = threadIdx.x;
  const int w = tid >> 6, lane = tid & 63;
  const int quad = lane >> 4, l15 = lane & 15;
  const int wr = w >> 2, wc = w & 3;

  // XCD swizzle: bx&7 = XCD. Per XCD: 2 m_blks x 8 j x 2 kc -> A strips (4 MiB) stay
  // L2-local AND kc-partners share an L2 (fast partner-partial reads in the tail).
  const int x = blockIdx.x & 7;
  const int t5 = blockIdx.x >> 3;            // [0,32)
  const int m_blk = x * 2 + (t5 >> 4);
  const int j_blk = t5 & 7;
  const int kc    = (t5 >> 3) & 1;
  const int mrow0 = m_blk << 8, jcol0 = j_blk << 7;

  const unsigned short* Ag = Ab + (size_t)mrow0 * 4096 + (kc << 11);
  const unsigned short* Bg = Yt + (size_t)jcol0 * 4096 + (kc << 11);

  // Staging offsets (chunk-XOR): slot s -> row = s>>3, kg = (s&7)^(row&7).
  int srcA[4], dstA[4], srcB[2], dstB[2];
#pragma unroll
  for (int r = 0; r < 4; ++r) {
    int s = r * 512 + tid, row = s >> 3, kg = (s & 7) ^ (row & 7);
    srcA[r] = row * 4096 + kg * 8;
    dstA[r] = (r * 512 + w * 64) * 8;        // wave-uniform LDS base (shorts)
  }
#pragma unroll
  for (int r = 0; r < 2; ++r) {
    int s = r * 512 + tid, row = s >> 3, kg = (s & 7) ^ (row & 7);
    srcB[r] = row * 4096 + kg * 8;
    dstB[r] = (r * 512 + w * 64) * 8;
  }

  // ds_read bases: fragment rows all have row&7 == l15&7 -> conflict-free chunks.
  const int c0 = (quad ^ (l15 & 7)) * 8;
  const int c1 = ((4 + quad) ^ (l15 & 7)) * 8;
  const int aB = (wr * 128 + l15) * 64;      // + i*1024 + c{0,1}, rel. A-buf
  const int bB = (wc * 32 + l15) * 64;       // + j*1024 + c{0,1}, rel. B-buf

  f32x4 acc[8][2];
#pragma unroll
  for (int i = 0; i < 8; ++i)
#pragma unroll
    for (int j = 0; j < 2; ++j) acc[i][j] = (f32x4){0.f, 0.f, 0.f, 0.f};

  // Prologue: A(0)->buf0, B(0)->bbuf0, A(1)->buf1, B(1)->bbuf1 (12 loads).
  // vmcnt(6): oldest 6 (= tile0) landed; tile1 still in flight.
  STAGE_A(0, 0) STAGE_B(0, 0) STAGE_A(1, 1) STAGE_B(1, 1)
  asm volatile("s_waitcnt vmcnt(6)" ::: "memory");
  __builtin_amdgcn_s_barrier();

  int ac = 0;                                // A-buf index = t % 3
  for (int t = 0; t < 32; ++t) {
    const unsigned short* la = lds + ac * 16384;
    const unsigned short* lb = lds + 49152 + (t & 1) * 8192;
    short8 bfr[2][2], afr[4][2];

    // ---- phase 1: all B-frags + A i0-3; issue A(t+2) (its buf died at t-1 ph2) ----
#pragma unroll
    for (int j = 0; j < 2; ++j) {
      bfr[j][0] = *(const short8*)&lb[bB + j * 1024 + c0];
      bfr[j][1] = *(const short8*)&lb[bB + j * 1024 + c1];
    }
#pragma unroll
    for (int i = 0; i < 4; ++i) {
      afr[i][0] = *(const short8*)&la[aB + i * 1024 + c0];
      afr[i][1] = *(const short8*)&la[aB + i * 1024 + c1];
    }
    if (t < 30) { int bt = ac + 2; if (bt >= 3) bt -= 3; STAGE_A(t + 2, bt) }
    PHASE_MFMA(0)

    // ---- phase 2: A i4-7 (bfr stays live in regs); issue B(t+2) (buf read in ph1);
    //      counted vmcnt once per K-tile: 12 in flight, oldest 6 = tile t+1. ----
#pragma unroll
    for (int i = 0; i < 4; ++i) {
      afr[i][0] = *(const short8*)&la[aB + (i + 4) * 1024 + c0];
      afr[i][1] = *(const short8*)&la[aB + (i + 4) * 1024 + c1];
    }
    if (t < 30) { STAGE_B(t + 2, t & 1) }
    if (t < 30)      { asm volatile("s_waitcnt vmcnt(6)" ::: "memory"); }
    else if (t == 30){ asm volatile("s_waitcnt vmcnt(0)" ::: "memory"); }
    PHASE_MFMA(4)

    ++ac; if (ac >= 3) ac = 0;
  }

  // ---- epilogue: store bf16 partial (C/D layout col=l15, row=quad*4+rg) ----
  unsigned short* P = Pb + (size_t)kc * ((size_t)NN * NJ);
#pragma unroll
  for (int i = 0; i < 8; ++i) {
    const int r0 = mrow0 + wr * 128 + i * 16 + quad * 4;
#pragma unroll
    for (int j = 0; j < 2; ++j) {
      const int jc = jcol0 + wc * 32 + j * 16 + l15;
      unsigned short* pp = P + (size_t)r0 * NJ + jc;
#pragma unroll
      for (int rg = 0; rg < 4; ++rg)
        pp[(size_t)rg * NJ] = f2bf(acc[i][j][rg]);
    }
  }

  // ---- fused split-K tail: second finisher reduces (own acc fp32 + partner bf16) ----
  __syncthreads();  // barrier semantics drain vmcnt: all partial stores complete
  if (tid == 0) {
    __threadfence();                          // release: L2 writeback (cross-XCD safe)
    int old = atomicAdd(&cnt[m_blk * 8 + j_blk], 1);   // device-scope
    ((volatile int*)lds)[0] = (old == 1);
  }
  __syncthreads();
  if (((const int*)lds)[0]) {
    __threadfence();                          // acquire: invalidate stale lines
    const unsigned short* Q = Pb + (size_t)(kc ^ 1) * ((size_t)NN * NJ);
#pragma unroll
    for (int i = 0; i < 8; ++i) {
      const int r0 = mrow0 + wr * 128 + i * 16 + quad * 4;
#pragma unroll
      for (int j = 0; j < 2; ++j) {
        const int jc = jcol0 + wc * 32 + j * 16 + l15;
        const int b = jc >> 6, e = jc & 63;
        const unsigned short* qq = Q + (size_t)r0 * NJ + jc;
        float* oo = out + ((size_t)b * NN + r0) * 64 + e;
#pragma unroll
        for (int rg = 0; rg < 4; ++rg)
          oo[(size_t)rg * 64] = acc[i][j][rg] + bf2f(qq[(size_t)rg * NJ]);
      }
    }
  }
}

extern "C" void kernel_launch(void* const* d_in, const int* in_sizes, int n_in,
                              void* d_out, int out_size, void* d_ws, size_t ws_size,
                              hipStream_t stream) {
  const float* Z = (const float*)d_in[0];   // [16][4096][64] fp32
  const float* A = (const float*)d_in[1];   // [4096][4096] fp32
  const float* W = (const float*)d_in[2];   // [64][64] fp32
  float* out = (float*)d_out;               // [16][4096][64] fp32

  unsigned short* Ab = (unsigned short*)d_ws;                                     // 32 MiB bf16 A
  unsigned short* Yt = (unsigned short*)((char*)d_ws + (size_t)32 * 1024 * 1024); // 8 MiB bf16 Y^T
  unsigned short* Pb = (unsigned short*)((char*)d_ws + (size_t)40 * 1024 * 1024); // 16 MiB bf16 partials x2
  int* cnt = (int*)((char*)d_ws + (size_t)56 * 1024 * 1024);                      // 128 counters

  k_prep<<<9216, 256, 0, stream>>>(A, Z, W, Ab, Yt, cnt);
  k_gemm<<<256, 512, 0, stream>>>(Ab, Yt, Pb, out, cnt);
}

// Round 3
// 191.383 us; speedup vs baseline: 1.0579x; 1.0579x over previous
//
#include <hip/hip_runtime.h>
#include <hip/hip_bf16.h>
#include <cstdint>

// Problem constants (B=16, N=4096, D_IN=D_OUT=64)
#define NB   16
#define NN   4096
#define ND   64
#define NJ   1024   // NB*ND columns of the big GEMM

typedef __attribute__((ext_vector_type(8))) short  short8;  // 8 bf16 = 4 VGPRs
typedef __attribute__((ext_vector_type(4))) float  f32x4;

__device__ __forceinline__ unsigned short f2bf(float f) {
  union { float f; unsigned int u; } v; v.f = f;
  unsigned int u = v.u;
  unsigned int r = u + 0x7FFFu + ((u >> 16) & 1u);  // round-to-nearest-even
  return (unsigned short)(r >> 16);
}
__device__ __forceinline__ float bf2f(unsigned short h) {
  union { unsigned int u; float f; } v; v.u = ((unsigned int)h) << 16; return v.f;
}

// ---------------- K1: merged prep = {A fp32->bf16 convert} + {Yt = (Z W)^T} --------
// bx < 8192: convert path (8 elems/thread, fully vectorized).
// bx >= 8192: zw path (1024 blocks). Block 8192 also zeroes the 64 split-K counters.
__global__ void k_prep(const float* __restrict__ A, const float* __restrict__ Z,
                       const float* __restrict__ W, unsigned short* __restrict__ Ab,
                       unsigned short* __restrict__ Yt, int* __restrict__ cnt) {
  int bx = blockIdx.x;
  if (bx < 8192) {
    int idx = bx * 256 + threadIdx.x;                // 2,097,152 threads exactly
    const float4* p = (const float4*)A + (size_t)idx * 2;
    float4 a = p[0], b = p[1];
    unsigned int w0 = (unsigned int)f2bf(a.x) | ((unsigned int)f2bf(a.y) << 16);
    unsigned int w1 = (unsigned int)f2bf(a.z) | ((unsigned int)f2bf(a.w) << 16);
    unsigned int w2 = (unsigned int)f2bf(b.x) | ((unsigned int)f2bf(b.y) << 16);
    unsigned int w3 = (unsigned int)f2bf(b.z) | ((unsigned int)f2bf(b.w) << 16);
    uint4 o; o.x = w0; o.y = w1; o.z = w2; o.w = w3;
    ((uint4*)Ab)[idx] = o;                           // 16B store
  } else {
    int bz = bx - 8192;                              // [0,1024)
    if (bz == 0 && threadIdx.x < 64) cnt[threadIdx.x] = 0;
    int lane = threadIdx.x & 63;
    int e0 = __builtin_amdgcn_readfirstlane((threadIdx.x >> 6) << 4);
    int b  = bz >> 6;                  // [0,16)
    int m0 = (bz & 63) << 6;           // [0,4096) step 64
    int m  = m0 + lane;
    const float* zr = Z + ((size_t)b * NN + m) * ND;
    float z[64];
#pragma unroll
    for (int g = 0; g < 16; ++g) *(float4*)&z[g * 4] = ((const float4*)zr)[g];
    float acc[16];
#pragma unroll
    for (int i = 0; i < 16; ++i) acc[i] = 0.f;
#pragma unroll
    for (int d = 0; d < 64; ++d) {
      float zd = z[d];
#pragma unroll
      for (int i = 0; i < 16; ++i) acc[i] += zd * W[d * 64 + e0 + i];  // uniform -> SMEM
    }
#pragma unroll
    for (int i = 0; i < 16; ++i)
      Yt[(size_t)(b * 64 + e0 + i) * NN + m] = f2bf(acc[i]);
  }
}

// ---------------- K2: 256x256-tile 8-phase GEMM (round-1 verified core, 40.4us) ----
// Grid 256 = 16m x 4j x 4kc, 1 block/CU, 512 thr = 8 waves (2M x 4N), per-wave 128x64.
// Appended: 4-way fused split-K tail (round-2's verified fence/atomic protocol).
// All 4 kc-partners share (m_blk,j_blk) -> same XCD (bx&7 = m_blk&7): partner partial
// reads are L2-local. 4th arrival reads 3 bf16 partials + own fp32 acc -> fp32 out.
__device__ __forceinline__ void gl2lds16(const unsigned short* g, unsigned short* l) {
  __builtin_amdgcn_global_load_lds(
      (const __attribute__((address_space(1))) unsigned int*)g,
      (__attribute__((address_space(3))) unsigned int*)l, 16, 0, 0);
}

#define STAGE2(GP, LP, H) \
  gl2lds16((GP) + sOff[H][0], (LP) + dBase[H][0]); \
  gl2lds16((GP) + sOff[H][1], (LP) + dBase[H][1]);

#define READ_A(I0) \
  afr[0][0] = *(const short8*)&lt[aBase + (I0) * 1024 + c0]; \
  afr[0][1] = *(const short8*)&lt[aBase + (I0) * 1024 + c1]; \
  afr[1][0] = *(const short8*)&lt[aBase + ((I0) + 1) * 1024 + c0]; \
  afr[1][1] = *(const short8*)&lt[aBase + ((I0) + 1) * 1024 + c1];

#define MFMA_Q(I0) \
  _Pragma("unroll") \
  for (int jj = 0; jj < 4; ++jj) { \
    acc[(I0)][jj]     = __builtin_amdgcn_mfma_f32_16x16x32_bf16(afr[0][0], bfr[jj][0], acc[(I0)][jj], 0, 0, 0); \
    acc[(I0)][jj]     = __builtin_amdgcn_mfma_f32_16x16x32_bf16(afr[0][1], bfr[jj][1], acc[(I0)][jj], 0, 0, 0); \
    acc[(I0) + 1][jj] = __builtin_amdgcn_mfma_f32_16x16x32_bf16(afr[1][0], bfr[jj][0], acc[(I0) + 1][jj], 0, 0, 0); \
    acc[(I0) + 1][jj] = __builtin_amdgcn_mfma_f32_16x16x32_bf16(afr[1][1], bfr[jj][1], acc[(I0) + 1][jj], 0, 0, 0); \
  }

#define PHASE_MFMA(I0) \
  __builtin_amdgcn_s_barrier(); \
  asm volatile("s_waitcnt lgkmcnt(0)" ::: "memory"); \
  __builtin_amdgcn_s_setprio(1); \
  MFMA_Q(I0) \
  __builtin_amdgcn_s_setprio(0); \
  __builtin_amdgcn_s_barrier();

__launch_bounds__(512, 2)  // 8 waves, 1 block/CU (128 KiB LDS), VGPR cap 256
__global__ void k_gemm(const unsigned short* __restrict__ Ab,
                       const unsigned short* __restrict__ Yt,
                       unsigned short* __restrict__ Pb,
                       float* __restrict__ out, int* __restrict__ cnt) {
  __shared__ unsigned short lds[65536];  // 128 KiB
  const int tid = threadIdx.x;
  const int w = tid >> 6, lane = tid & 63;
  const int quad = lane >> 4, l15 = lane & 15;
  const int wr = w >> 2, wc = w & 3;

  const int m_blk = blockIdx.x & 15;         // XCD = bx%8 = m_blk&7: 4 j_blks share
  const int j_blk = (blockIdx.x >> 4) & 3;   // one A strip per XCD L2 (2 m-strips = 4 MiB)
  const int kc    = blockIdx.x >> 6;
  const int mrow0 = m_blk << 8, jcol0 = j_blk << 8, kbase = kc << 10;

  const unsigned short* Ag = Ab + (size_t)mrow0 * 4096 + kbase;
  const unsigned short* Bg = Yt + (size_t)jcol0 * 4096 + kbase;

  // Staging offsets: half h, round r -> uniform LDS slot base h*1024+r*512+w*64,
  // per-lane slot s = base+lane, global source (row=s>>3, kg=(s&7)^(row&7)).
  int sOff[2][2], dBase[2][2];
#pragma unroll
  for (int h = 0; h < 2; ++h)
#pragma unroll
    for (int r = 0; r < 2; ++r) {
      int s = h * 1024 + r * 512 + w * 64 + lane;
      int row = s >> 3;
      int kg = (s & 7) ^ (row & 7);
      sOff[h][r]  = row * 4096 + kg * 8;
      dBase[h][r] = (h * 1024 + r * 512 + w * 64) * 8;  // wave-uniform (shorts)
    }

  // ds_read chunk offsets (shorts): row&7 == l15&7 for all fragment rows.
  const int c0 = (quad ^ (l15 & 7)) * 8;
  const int c1 = ((4 + quad) ^ (l15 & 7)) * 8;
  const int aBase = (wr * 128 + l15) * 64;            // + i*1024 + c{0,1}
  const int bBase = 32768 + (wc * 64 + l15) * 64;     // + j*1024 + c{0,1} (rel. lds+p*16384)

  f32x4 acc[8][4];
#pragma unroll
  for (int i = 0; i < 8; ++i)
#pragma unroll
    for (int j = 0; j < 4; ++j) acc[i][j] = (f32x4){0.f, 0.f, 0.f, 0.f};

  // Prologue: tile0 A+B -> buf0 (8 loads), tile1 B -> buf1 (4 loads).
  // vmcnt(4): tile0 landed, tile1-B still in flight.
  STAGE2(Ag, lds, 0) STAGE2(Ag, lds, 1)
  STAGE2(Bg, lds + 32768, 0) STAGE2(Bg, lds + 32768, 1)
  STAGE2(Bg + 64, lds + 49152, 0) STAGE2(Bg + 64, lds + 49152, 1)
  asm volatile("s_waitcnt vmcnt(4)" ::: "memory");
  __builtin_amdgcn_s_barrier();

  for (int t = 0; t < 16; ++t) {
    const int p = t & 1;
    const unsigned short* lt = lds + p * 16384;
    short8 bfr[4][2], afr[2][2];

    // ---- phase 1: all B-frags + A-quad0; issue A(t+1) halves 0,1 ----
#pragma unroll
    for (int j = 0; j < 4; ++j) {
      bfr[j][0] = *(const short8*)&lt[bBase + j * 1024 + c0];
      bfr[j][1] = *(const short8*)&lt[bBase + j * 1024 + c1];
    }
    READ_A(0)
    if (t < 15) {
      const unsigned short* g = Ag + (t + 1) * 64;
      unsigned short* lb = lds + (p ^ 1) * 16384;
      STAGE2(g, lb, 0) STAGE2(g, lb, 1)
    }
    PHASE_MFMA(0)

    // ---- phase 2: A-quad1; issue B(t+2) half 0 (tile-t B region is dead) ----
    READ_A(2)
    if (t < 14) {
      const unsigned short* g = Bg + (t + 2) * 64;
      unsigned short* lb = lds + 32768 + p * 16384;
      STAGE2(g, lb, 0)
    }
    PHASE_MFMA(2)

    // ---- phase 3: A-quad2; issue B(t+2) half 1 ----
    READ_A(4)
    if (t < 14) {
      const unsigned short* g = Bg + (t + 2) * 64;
      unsigned short* lb = lds + 32768 + p * 16384;
      STAGE2(g, lb, 1)
    }
    PHASE_MFMA(4)

    // ---- phase 4: A-quad3; counted vmcnt once per K-tile ----
    READ_A(6)
    if (t < 14) { asm volatile("s_waitcnt vmcnt(4)" ::: "memory"); }
    else if (t == 14) { asm volatile("s_waitcnt vmcnt(0)" ::: "memory"); }
    PHASE_MFMA(6)
  }

  // ---- epilogue: store bf16 partial (C/D layout col=l15, row=quad*4+rg) ----
  unsigned short* P = Pb + (size_t)kc * ((size_t)NN * NJ);
  const int r0base = mrow0 + wr * 128;
  const int cb = jcol0 + wc * 64;
#pragma unroll
  for (int i = 0; i < 8; ++i) {
    const int r0 = r0base + i * 16 + quad * 4;
#pragma unroll
    for (int j = 0; j < 4; ++j) {
      const int jc = cb + j * 16 + l15;
      unsigned short* pp = P + (size_t)r0 * NJ + jc;
#pragma unroll
      for (int rg = 0; rg < 4; ++rg)
        pp[(size_t)rg * NJ] = f2bf(acc[i][j][rg]);
    }
  }

  // ---- fused split-K tail: 4th arrival reduces (own fp32 acc + 3 bf16 partials) ----
  __syncthreads();  // compiler drains vmcnt/LDS: partial stores complete, LDS reusable
  if (tid == 0) {
    __threadfence();                          // release: partial visible before ticket
    int old = atomicAdd(&cnt[m_blk * 4 + j_blk], 1);   // device-scope
    ((volatile int*)lds)[0] = (old == 3);
  }
  __syncthreads();
  if (((const int*)lds)[0]) {
    __threadfence();                          // acquire: see partners' partials
    const unsigned short* Q1 = Pb + (size_t)((kc + 1) & 3) * ((size_t)NN * NJ);
    const unsigned short* Q2 = Pb + (size_t)((kc + 2) & 3) * ((size_t)NN * NJ);
    const unsigned short* Q3 = Pb + (size_t)((kc + 3) & 3) * ((size_t)NN * NJ);
#pragma unroll
    for (int i = 0; i < 8; ++i) {
      const int r0 = r0base + i * 16 + quad * 4;
#pragma unroll
      for (int j = 0; j < 4; ++j) {
        const int jc = cb + j * 16 + l15;
        const int b = jc >> 6, e = jc & 63;
        const size_t off = (size_t)r0 * NJ + jc;
        float* oo = out + ((size_t)b * NN + r0) * 64 + e;
#pragma unroll
        for (int rg = 0; rg < 4; ++rg) {
          const size_t o2 = off + (size_t)rg * NJ;
          oo[(size_t)rg * 64] = acc[i][j][rg] + bf2f(Q1[o2]) + bf2f(Q2[o2]) + bf2f(Q3[o2]);
        }
      }
    }
  }
}

extern "C" void kernel_launch(void* const* d_in, const int* in_sizes, int n_in,
                              void* d_out, int out_size, void* d_ws, size_t ws_size,
                              hipStream_t stream) {
  const float* Z = (const float*)d_in[0];   // [16][4096][64] fp32
  const float* A = (const float*)d_in[1];   // [4096][4096] fp32
  const float* W = (const float*)d_in[2];   // [64][64] fp32
  float* out = (float*)d_out;               // [16][4096][64] fp32

  unsigned short* Ab = (unsigned short*)d_ws;                                     // 32 MiB bf16 A
  unsigned short* Yt = (unsigned short*)((char*)d_ws + (size_t)32 * 1024 * 1024); // 8 MiB bf16 Y^T
  unsigned short* Pb = (unsigned short*)((char*)d_ws + (size_t)40 * 1024 * 1024); // 32 MiB bf16 partials x4
  int* cnt = (int*)((char*)d_ws + (size_t)72 * 1024 * 1024);                      // 64 counters

  k_prep<<<9216, 256, 0, stream>>>(A, Z, W, Ab, Yt, cnt);
  k_gemm<<<256, 512, 0, stream>>>(Ab, Yt, Pb, out, cnt);
}

// Round 4
// 166.975 us; speedup vs baseline: 1.2125x; 1.1462x over previous
//
#include <hip/hip_runtime.h>
#include <hip/hip_bf16.h>
#include <cstdint>

// Problem constants (B=16, N=4096, D_IN=D_OUT=64)
#define NB   16
#define NN   4096
#define ND   64
#define NJ   1024   // NB*ND columns of the big GEMM

typedef __attribute__((ext_vector_type(8))) short  short8;  // 8 bf16 = 4 VGPRs
typedef __attribute__((ext_vector_type(4))) float  f32x4;

__device__ __forceinline__ unsigned short f2bf(float f) {
  union { float f; unsigned int u; } v; v.f = f;
  unsigned int u = v.u;
  unsigned int r = u + 0x7FFFu + ((u >> 16) & 1u);  // round-to-nearest-even
  return (unsigned short)(r >> 16);
}
__device__ __forceinline__ float bf2f(unsigned short h) {
  union { unsigned int u; float f; } v; v.u = ((unsigned int)h) << 16; return v.f;
}

// ---------------- K1: merged prep = {A fp32->bf16 convert} + {Yt = (Z W)^T} --------
// bx < 8192: convert path (8 elems/thread, fully vectorized).
// bx >= 8192: zw path (1024 blocks).
__global__ void k_prep(const float* __restrict__ A, const float* __restrict__ Z,
                       const float* __restrict__ W, unsigned short* __restrict__ Ab,
                       unsigned short* __restrict__ Yt) {
  int bx = blockIdx.x;
  if (bx < 8192) {
    int idx = bx * 256 + threadIdx.x;                // 2,097,152 threads exactly
    const float4* p = (const float4*)A + (size_t)idx * 2;
    float4 a = p[0], b = p[1];
    unsigned int w0 = (unsigned int)f2bf(a.x) | ((unsigned int)f2bf(a.y) << 16);
    unsigned int w1 = (unsigned int)f2bf(a.z) | ((unsigned int)f2bf(a.w) << 16);
    unsigned int w2 = (unsigned int)f2bf(b.x) | ((unsigned int)f2bf(b.y) << 16);
    unsigned int w3 = (unsigned int)f2bf(b.z) | ((unsigned int)f2bf(b.w) << 16);
    uint4 o; o.x = w0; o.y = w1; o.z = w2; o.w = w3;
    ((uint4*)Ab)[idx] = o;                           // 16B store
  } else {
    int bz = bx - 8192;                              // [0,1024)
    int lane = threadIdx.x & 63;
    int e0 = __builtin_amdgcn_readfirstlane((threadIdx.x >> 6) << 4);
    int b  = bz >> 6;                  // [0,16)
    int m0 = (bz & 63) << 6;           // [0,4096) step 64
    int m  = m0 + lane;
    const float* zr = Z + ((size_t)b * NN + m) * ND;
    float z[64];
#pragma unroll
    for (int g = 0; g < 16; ++g) *(float4*)&z[g * 4] = ((const float4*)zr)[g];
    float acc[16];
#pragma unroll
    for (int i = 0; i < 16; ++i) acc[i] = 0.f;
#pragma unroll
    for (int d = 0; d < 64; ++d) {
      float zd = z[d];
#pragma unroll
      for (int i = 0; i < 16; ++i) acc[i] += zd * W[d * 64 + e0 + i];  // uniform -> SMEM
    }
#pragma unroll
    for (int i = 0; i < 16; ++i)
      Yt[(size_t)(b * 64 + e0 + i) * NN + m] = f2bf(acc[i]);
  }
}

// ---------------- K2: 256x256-tile 8-phase GEMM (round-1 verified core) -------------
// Grid 256 = 16m x 4j x 4kc, 1 block/CU, 512 thr = 8 waves (2M x 4N), per-wave 128x64.
// Plain bf16 partial stores (no fused tail: round-3 showed the fused reduce costs
// ~37us by concentrating 40MB of scalar traffic on 64 CUs after an L2 invalidate).
// A/B delta this round: no explicit lgkmcnt(0) full-drain per phase — every ds_read
// result is an MFMA operand in the same phase, so compiler-inserted fine-grained
// lgkmcnt(N) waits subsume the drain; first MFMA issues as soon as its operands land.
__device__ __forceinline__ void gl2lds16(const unsigned short* g, unsigned short* l) {
  __builtin_amdgcn_global_load_lds(
      (const __attribute__((address_space(1))) unsigned int*)g,
      (__attribute__((address_space(3))) unsigned int*)l, 16, 0, 0);
}

#define STAGE2(GP, LP, H) \
  gl2lds16((GP) + sOff[H][0], (LP) + dBase[H][0]); \
  gl2lds16((GP) + sOff[H][1], (LP) + dBase[H][1]);

#define READ_A(I0) \
  afr[0][0] = *(const short8*)&lt[aBase + (I0) * 1024 + c0]; \
  afr[0][1] = *(const short8*)&lt[aBase + (I0) * 1024 + c1]; \
  afr[1][0] = *(const short8*)&lt[aBase + ((I0) + 1) * 1024 + c0]; \
  afr[1][1] = *(const short8*)&lt[aBase + ((I0) + 1) * 1024 + c1];

#define MFMA_Q(I0) \
  _Pragma("unroll") \
  for (int jj = 0; jj < 4; ++jj) { \
    acc[(I0)][jj]     = __builtin_amdgcn_mfma_f32_16x16x32_bf16(afr[0][0], bfr[jj][0], acc[(I0)][jj], 0, 0, 0); \
    acc[(I0)][jj]     = __builtin_amdgcn_mfma_f32_16x16x32_bf16(afr[0][1], bfr[jj][1], acc[(I0)][jj], 0, 0, 0); \
    acc[(I0) + 1][jj] = __builtin_amdgcn_mfma_f32_16x16x32_bf16(afr[1][0], bfr[jj][0], acc[(I0) + 1][jj], 0, 0, 0); \
    acc[(I0) + 1][jj] = __builtin_amdgcn_mfma_f32_16x16x32_bf16(afr[1][1], bfr[jj][1], acc[(I0) + 1][jj], 0, 0, 0); \
  }

#define PHASE_MFMA(I0) \
  __builtin_amdgcn_s_barrier(); \
  asm volatile("" ::: "memory"); /* compiler fence only; HW waits are data-dep lgkmcnt(N) */ \
  __builtin_amdgcn_s_setprio(1); \
  MFMA_Q(I0) \
  __builtin_amdgcn_s_setprio(0); \
  __builtin_amdgcn_s_barrier();

__launch_bounds__(512, 2)  // 8 waves, 1 block/CU (128 KiB LDS), VGPR cap 256
__global__ void k_gemm(const unsigned short* __restrict__ Ab,
                       const unsigned short* __restrict__ Yt,
                       unsigned short* __restrict__ Pb) {
  __shared__ unsigned short lds[65536];  // 128 KiB
  const int tid = threadIdx.x;
  const int w = tid >> 6, lane = tid & 63;
  const int quad = lane >> 4, l15 = lane & 15;
  const int wr = w >> 2, wc = w & 3;

  const int m_blk = blockIdx.x & 15;         // XCD = bx%8 = m_blk&7: 4 j_blks share
  const int j_blk = (blockIdx.x >> 4) & 3;   // one A strip per XCD L2
  const int kc    = blockIdx.x >> 6;
  const int mrow0 = m_blk << 8, jcol0 = j_blk << 8, kbase = kc << 10;

  const unsigned short* Ag = Ab + (size_t)mrow0 * 4096 + kbase;
  const unsigned short* Bg = Yt + (size_t)jcol0 * 4096 + kbase;

  // Staging offsets: half h, round r -> uniform LDS slot base h*1024+r*512+w*64,
  // per-lane slot s = base+lane, global source (row=s>>3, kg=(s&7)^(row&7)).
  int sOff[2][2], dBase[2][2];
#pragma unroll
  for (int h = 0; h < 2; ++h)
#pragma unroll
    for (int r = 0; r < 2; ++r) {
      int s = h * 1024 + r * 512 + w * 64 + lane;
      int row = s >> 3;
      int kg = (s & 7) ^ (row & 7);
      sOff[h][r]  = row * 4096 + kg * 8;
      dBase[h][r] = (h * 1024 + r * 512 + w * 64) * 8;  // wave-uniform (shorts)
    }

  // ds_read chunk offsets (shorts): row&7 == l15&7 for all fragment rows.
  const int c0 = (quad ^ (l15 & 7)) * 8;
  const int c1 = ((4 + quad) ^ (l15 & 7)) * 8;
  const int aBase = (wr * 128 + l15) * 64;            // + i*1024 + c{0,1}
  const int bBase = 32768 + (wc * 64 + l15) * 64;     // + j*1024 + c{0,1} (rel. lds+p*16384)

  f32x4 acc[8][4];
#pragma unroll
  for (int i = 0; i < 8; ++i)
#pragma unroll
    for (int j = 0; j < 4; ++j) acc[i][j] = (f32x4){0.f, 0.f, 0.f, 0.f};

  // Prologue: tile0 A+B -> buf0 (8 loads), tile1 B -> buf1 (4 loads).
  // vmcnt(4): tile0 landed, tile1-B still in flight.
  STAGE2(Ag, lds, 0) STAGE2(Ag, lds, 1)
  STAGE2(Bg, lds + 32768, 0) STAGE2(Bg, lds + 32768, 1)
  STAGE2(Bg + 64, lds + 49152, 0) STAGE2(Bg + 64, lds + 49152, 1)
  asm volatile("s_waitcnt vmcnt(4)" ::: "memory");
  __builtin_amdgcn_s_barrier();

  for (int t = 0; t < 16; ++t) {
    const int p = t & 1;
    const unsigned short* lt = lds + p * 16384;
    short8 bfr[4][2], afr[2][2];

    // ---- phase 1: all B-frags + A-quad0; issue A(t+1) halves 0,1 ----
#pragma unroll
    for (int j = 0; j < 4; ++j) {
      bfr[j][0] = *(const short8*)&lt[bBase + j * 1024 + c0];
      bfr[j][1] = *(const short8*)&lt[bBase + j * 1024 + c1];
    }
    READ_A(0)
    if (t < 15) {
      const unsigned short* g = Ag + (t + 1) * 64;
      unsigned short* lb = lds + (p ^ 1) * 16384;
      STAGE2(g, lb, 0) STAGE2(g, lb, 1)
    }
    PHASE_MFMA(0)

    // ---- phase 2: A-quad1; issue B(t+2) half 0 (tile-t B region read in ph1) ----
    READ_A(2)
    if (t < 14) {
      const unsigned short* g = Bg + (t + 2) * 64;
      unsigned short* lb = lds + 32768 + p * 16384;
      STAGE2(g, lb, 0)
    }
    PHASE_MFMA(2)

    // ---- phase 3: A-quad2; issue B(t+2) half 1 ----
    READ_A(4)
    if (t < 14) {
      const unsigned short* g = Bg + (t + 2) * 64;
      unsigned short* lb = lds + 32768 + p * 16384;
      STAGE2(g, lb, 1)
    }
    PHASE_MFMA(4)

    // ---- phase 4: A-quad3; counted vmcnt once per K-tile (never 0 mid-loop) ----
    READ_A(6)
    if (t < 14) { asm volatile("s_waitcnt vmcnt(4)" ::: "memory"); }
    else if (t == 14) { asm volatile("s_waitcnt vmcnt(0)" ::: "memory"); }
    PHASE_MFMA(6)
  }

  // Epilogue: C/D layout col=l15, row=quad*4+reg (m89/m91-verified mapping).
  unsigned short* P = Pb + (size_t)kc * ((size_t)NN * NJ);
  const int r0base = mrow0 + wr * 128;
  const int cb = jcol0 + wc * 64;
#pragma unroll
  for (int i = 0; i < 8; ++i) {
    const int r0 = r0base + i * 16 + quad * 4;
#pragma unroll
    for (int j = 0; j < 4; ++j) {
      const int jc = cb + j * 16 + l15;
      unsigned short* pp = P + (size_t)r0 * NJ + jc;
#pragma unroll
      for (int rg = 0; rg < 4; ++rg)
        pp[(size_t)rg * NJ] = f2bf(acc[i][j][rg]);
    }
  }
}

// ---------------- K3: out[m-major] = sum_kc P[kc]; 8 floats/thread ------------------
// All 256 CUs, coalesced 16B loads: the distributed reduce the fused tail failed at.
__global__ void k_reduce(const unsigned short* __restrict__ P, float* __restrict__ out) {
  int t = blockIdx.x * 256 + threadIdx.x;      // 524,288 threads exactly
  size_t of = (size_t)t * 8;                   // out flat index (8 consecutive floats)
  int bidx = t >> 15;                          // of >> 18
  int rem  = (int)(of & 262143);               // within one batch: m*64 + e
  int m = rem >> 6, e = rem & 63;
  size_t pj = (size_t)m * NJ + bidx * 64 + e;  // P row-index: [m][j= bidx*64+e]
  float s[8];
#pragma unroll
  for (int u = 0; u < 8; ++u) s[u] = 0.f;
#pragma unroll
  for (int kc = 0; kc < 4; ++kc) {
    short8 v = *(const short8*)(P + (size_t)kc * (NN * NJ) + pj);  // 16B load
#pragma unroll
    for (int u = 0; u < 8; ++u) s[u] += bf2f((unsigned short)v[u]);
  }
  float4 o0 = {s[0], s[1], s[2], s[3]}, o1 = {s[4], s[5], s[6], s[7]};
  ((float4*)(out + of))[0] = o0;
  ((float4*)(out + of))[1] = o1;
}

extern "C" void kernel_launch(void* const* d_in, const int* in_sizes, int n_in,
                              void* d_out, int out_size, void* d_ws, size_t ws_size,
                              hipStream_t stream) {
  const float* Z = (const float*)d_in[0];   // [16][4096][64] fp32
  const float* A = (const float*)d_in[1];   // [4096][4096] fp32
  const float* W = (const float*)d_in[2];   // [64][64] fp32
  float* out = (float*)d_out;               // [16][4096][64] fp32

  unsigned short* Ab = (unsigned short*)d_ws;                                     // 32 MiB bf16 A
  unsigned short* Yt = (unsigned short*)((char*)d_ws + (size_t)32 * 1024 * 1024); // 8 MiB bf16 Y^T
  unsigned short* Pb = (unsigned short*)((char*)d_ws + (size_t)40 * 1024 * 1024); // 32 MiB bf16 partials x4

  k_prep<<<9216, 256, 0, stream>>>(A, Z, W, Ab, Yt);
  k_gemm<<<256, 512, 0, stream>>>(Ab, Yt, Pb);
  k_reduce<<<2048, 256, 0, stream>>>(Pb, out);
}

// Round 5
// 155.409 us; speedup vs baseline: 1.3027x; 1.0744x over previous
//
#include <hip/hip_runtime.h>
#include <hip/hip_bf16.h>
#include <cstdint>

// Problem constants (B=16, N=4096, D_IN=D_OUT=64)
#define NB   16
#define NN   4096
#define ND   64
#define NJ   1024   // NB*ND columns of the big GEMM

typedef __attribute__((ext_vector_type(8))) short  short8;  // 8 bf16 = 4 VGPRs
typedef __attribute__((ext_vector_type(4))) float  f32x4;

__device__ __forceinline__ unsigned short f2bf(float f) {
  union { float f; unsigned int u; } v; v.f = f;
  unsigned int u = v.u;
  unsigned int r = u + 0x7FFFu + ((u >> 16) & 1u);  // round-to-nearest-even
  return (unsigned short)(r >> 16);
}
__device__ __forceinline__ float bf2f(unsigned short h) {
  union { unsigned int u; float f; } v; v.u = ((unsigned int)h) << 16; return v.f;
}

// ---------------- K1: merged prep = {Yt = (Z W)^T} + {A fp32->bf16 convert} --------
// zw blocks FIRST (bx < 1024): they are latency-bound (W s_load chain) and hide
// under the BW-bound convert stream instead of serializing after it (round-4: zw
// tail cost ~27us of k_prep's 43us).
// zw path: Z-tile staged via LDS with fully coalesced float4 loads (round-4's direct
// loads were 64-segment uncoalesced: lane l read stride-256B addresses).
// zs stride 65: staging writes and compute reads both land 2 lanes/bank (free).
__global__ void k_prep(const float* __restrict__ A, const float* __restrict__ Z,
                       const float* __restrict__ W, unsigned short* __restrict__ Ab,
                       unsigned short* __restrict__ Yt) {
  __shared__ float zs[64 * 65];                      // 16.25 KiB (zw blocks only)
  int bx = blockIdx.x;
  int tid = threadIdx.x;
  if (bx < 1024) {
    int b  = bx >> 6;                  // [0,16)
    int m0 = (bx & 63) << 6;           // [0,4096) step 64
    // ---- stage Z[b][m0:m0+64][0:64] -> zs, coalesced: 16 thr/row, 4 rounds ----
    const float* zb = Z + ((size_t)b * NN + m0) * ND;
#pragma unroll
    for (int r = 0; r < 4; ++r) {
      int row = r * 16 + (tid >> 4);
      int col = (tid & 15) * 4;
      float4 v = *(const float4*)(zb + (size_t)row * ND + col);
      float* d = &zs[row * 65 + col];
      d[0] = v.x; d[1] = v.y; d[2] = v.z; d[3] = v.w;   // 4x b32: 2 lanes/bank, free
    }
    __syncthreads();
    int lane = tid & 63;                               // = m-row within tile
    int e0 = __builtin_amdgcn_readfirstlane((tid >> 6) << 4);  // wave-uniform -> s_load W
    int m  = m0 + lane;
    float acc[16];
#pragma unroll
    for (int i = 0; i < 16; ++i) acc[i] = 0.f;
#pragma unroll
    for (int d = 0; d < 64; ++d) {
      float zd = zs[lane * 65 + d];                    // bank (lane+d)&31: free
#pragma unroll
      for (int i = 0; i < 16; ++i) acc[i] += zd * W[d * 64 + e0 + i];  // uniform -> SMEM
    }
#pragma unroll
    for (int i = 0; i < 16; ++i)
      Yt[(size_t)(b * 64 + e0 + i) * NN + m] = f2bf(acc[i]);
  } else {
    int idx = (bx - 1024) * 256 + tid;               // 2,097,152 threads exactly
    const float4* p = (const float4*)A + (size_t)idx * 2;
    float4 a = p[0], b = p[1];
    unsigned int w0 = (unsigned int)f2bf(a.x) | ((unsigned int)f2bf(a.y) << 16);
    unsigned int w1 = (unsigned int)f2bf(a.z) | ((unsigned int)f2bf(a.w) << 16);
    unsigned int w2 = (unsigned int)f2bf(b.x) | ((unsigned int)f2bf(b.y) << 16);
    unsigned int w3 = (unsigned int)f2bf(b.z) | ((unsigned int)f2bf(b.w) << 16);
    uint4 o; o.x = w0; o.y = w1; o.z = w2; o.w = w3;
    ((uint4*)Ab)[idx] = o;                           // 16B store
  }
}

// ---------------- K2: 256x256-tile 8-phase GEMM (round-1 verified core) -------------
// Grid 256 = 16m x 4j x 4kc, 1 block/CU, 512 thr = 8 waves (2M x 4N), per-wave 128x64.
// Plain bf16 partial stores. No explicit lgkmcnt(0) per phase (round-4: passed,
// k_gemm <= 40.3us): compiler-inserted data-dep lgkmcnt(N) waits subsume the drain.
__device__ __forceinline__ void gl2lds16(const unsigned short* g, unsigned short* l) {
  __builtin_amdgcn_global_load_lds(
      (const __attribute__((address_space(1))) unsigned int*)g,
      (__attribute__((address_space(3))) unsigned int*)l, 16, 0, 0);
}

#define STAGE2(GP, LP, H) \
  gl2lds16((GP) + sOff[H][0], (LP) + dBase[H][0]); \
  gl2lds16((GP) + sOff[H][1], (LP) + dBase[H][1]);

#define READ_A(I0) \
  afr[0][0] = *(const short8*)&lt[aBase + (I0) * 1024 + c0]; \
  afr[0][1] = *(const short8*)&lt[aBase + (I0) * 1024 + c1]; \
  afr[1][0] = *(const short8*)&lt[aBase + ((I0) + 1) * 1024 + c0]; \
  afr[1][1] = *(const short8*)&lt[aBase + ((I0) + 1) * 1024 + c1];

#define MFMA_Q(I0) \
  _Pragma("unroll") \
  for (int jj = 0; jj < 4; ++jj) { \
    acc[(I0)][jj]     = __builtin_amdgcn_mfma_f32_16x16x32_bf16(afr[0][0], bfr[jj][0], acc[(I0)][jj], 0, 0, 0); \
    acc[(I0)][jj]     = __builtin_amdgcn_mfma_f32_16x16x32_bf16(afr[0][1], bfr[jj][1], acc[(I0)][jj], 0, 0, 0); \
    acc[(I0) + 1][jj] = __builtin_amdgcn_mfma_f32_16x16x32_bf16(afr[1][0], bfr[jj][0], acc[(I0) + 1][jj], 0, 0, 0); \
    acc[(I0) + 1][jj] = __builtin_amdgcn_mfma_f32_16x16x32_bf16(afr[1][1], bfr[jj][1], acc[(I0) + 1][jj], 0, 0, 0); \
  }

#define PHASE_MFMA(I0) \
  __builtin_amdgcn_s_barrier(); \
  asm volatile("" ::: "memory"); /* compiler fence; HW waits are data-dep lgkmcnt(N) */ \
  __builtin_amdgcn_s_setprio(1); \
  MFMA_Q(I0) \
  __builtin_amdgcn_s_setprio(0); \
  __builtin_amdgcn_s_barrier();

__launch_bounds__(512, 2)  // 8 waves, 1 block/CU (128 KiB LDS), VGPR cap 256
__global__ void k_gemm(const unsigned short* __restrict__ Ab,
                       const unsigned short* __restrict__ Yt,
                       unsigned short* __restrict__ Pb) {
  __shared__ unsigned short lds[65536];  // 128 KiB
  const int tid = threadIdx.x;
  const int w = tid >> 6, lane = tid & 63;
  const int quad = lane >> 4, l15 = lane & 15;
  const int wr = w >> 2, wc = w & 3;

  const int m_blk = blockIdx.x & 15;         // XCD = bx%8 = m_blk&7: 4 j_blks share
  const int j_blk = (blockIdx.x >> 4) & 3;   // one A strip per XCD L2
  const int kc    = blockIdx.x >> 6;
  const int mrow0 = m_blk << 8, jcol0 = j_blk << 8, kbase = kc << 10;

  const unsigned short* Ag = Ab + (size_t)mrow0 * 4096 + kbase;
  const unsigned short* Bg = Yt + (size_t)jcol0 * 4096 + kbase;

  // Staging offsets: half h, round r -> uniform LDS slot base h*1024+r*512+w*64,
  // per-lane slot s = base+lane, global source (row=s>>3, kg=(s&7)^(row&7)).
  int sOff[2][2], dBase[2][2];
#pragma unroll
  for (int h = 0; h < 2; ++h)
#pragma unroll
    for (int r = 0; r < 2; ++r) {
      int s = h * 1024 + r * 512 + w * 64 + lane;
      int row = s >> 3;
      int kg = (s & 7) ^ (row & 7);
      sOff[h][r]  = row * 4096 + kg * 8;
      dBase[h][r] = (h * 1024 + r * 512 + w * 64) * 8;  // wave-uniform (shorts)
    }

  // ds_read chunk offsets (shorts): row&7 == l15&7 for all fragment rows.
  const int c0 = (quad ^ (l15 & 7)) * 8;
  const int c1 = ((4 + quad) ^ (l15 & 7)) * 8;
  const int aBase = (wr * 128 + l15) * 64;            // + i*1024 + c{0,1}
  const int bBase = 32768 + (wc * 64 + l15) * 64;     // + j*1024 + c{0,1} (rel. lds+p*16384)

  f32x4 acc[8][4];
#pragma unroll
  for (int i = 0; i < 8; ++i)
#pragma unroll
    for (int j = 0; j < 4; ++j) acc[i][j] = (f32x4){0.f, 0.f, 0.f, 0.f};

  // Prologue: tile0 A+B -> buf0 (8 loads), tile1 B -> buf1 (4 loads).
  // vmcnt(4): tile0 landed, tile1-B still in flight.
  STAGE2(Ag, lds, 0) STAGE2(Ag, lds, 1)
  STAGE2(Bg, lds + 32768, 0) STAGE2(Bg, lds + 32768, 1)
  STAGE2(Bg + 64, lds + 49152, 0) STAGE2(Bg + 64, lds + 49152, 1)
  asm volatile("s_waitcnt vmcnt(4)" ::: "memory");
  __builtin_amdgcn_s_barrier();

  for (int t = 0; t < 16; ++t) {
    const int p = t & 1;
    const unsigned short* lt = lds + p * 16384;
    short8 bfr[4][2], afr[2][2];

    // ---- phase 1: all B-frags + A-quad0; issue A(t+1) halves 0,1 ----
#pragma unroll
    for (int j = 0; j < 4; ++j) {
      bfr[j][0] = *(const short8*)&lt[bBase + j * 1024 + c0];
      bfr[j][1] = *(const short8*)&lt[bBase + j * 1024 + c1];
    }
    READ_A(0)
    if (t < 15) {
      const unsigned short* g = Ag + (t + 1) * 64;
      unsigned short* lb = lds + (p ^ 1) * 16384;
      STAGE2(g, lb, 0) STAGE2(g, lb, 1)
    }
    PHASE_MFMA(0)

    // ---- phase 2: A-quad1; issue B(t+2) half 0 (tile-t B region read in ph1) ----
    READ_A(2)
    if (t < 14) {
      const unsigned short* g = Bg + (t + 2) * 64;
      unsigned short* lb = lds + 32768 + p * 16384;
      STAGE2(g, lb, 0)
    }
    PHASE_MFMA(2)

    // ---- phase 3: A-quad2; issue B(t+2) half 1 ----
    READ_A(4)
    if (t < 14) {
      const unsigned short* g = Bg + (t + 2) * 64;
      unsigned short* lb = lds + 32768 + p * 16384;
      STAGE2(g, lb, 1)
    }
    PHASE_MFMA(4)

    // ---- phase 4: A-quad3; counted vmcnt once per K-tile (never 0 mid-loop) ----
    READ_A(6)
    if (t < 14) { asm volatile("s_waitcnt vmcnt(4)" ::: "memory"); }
    else if (t == 14) { asm volatile("s_waitcnt vmcnt(0)" ::: "memory"); }
    PHASE_MFMA(6)
  }

  // Epilogue: C/D layout col=l15, row=quad*4+reg (m89/m91-verified mapping).
  unsigned short* P = Pb + (size_t)kc * ((size_t)NN * NJ);
  const int r0base = mrow0 + wr * 128;
  const int cb = jcol0 + wc * 64;
#pragma unroll
  for (int i = 0; i < 8; ++i) {
    const int r0 = r0base + i * 16 + quad * 4;
#pragma unroll
    for (int j = 0; j < 4; ++j) {
      const int jc = cb + j * 16 + l15;
      unsigned short* pp = P + (size_t)r0 * NJ + jc;
#pragma unroll
      for (int rg = 0; rg < 4; ++rg)
        pp[(size_t)rg * NJ] = f2bf(acc[i][j][rg]);
    }
  }
}

// ---------------- K3: out[m-major] = sum_kc P[kc]; 8 floats/thread ------------------
__global__ void k_reduce(const unsigned short* __restrict__ P, float* __restrict__ out) {
  int t = blockIdx.x * 256 + threadIdx.x;      // 524,288 threads exactly
  size_t of = (size_t)t * 8;                   // out flat index (8 consecutive floats)
  int bidx = t >> 15;                          // of >> 18
  int rem  = (int)(of & 262143);               // within one batch: m*64 + e
  int m = rem >> 6, e = rem & 63;
  size_t pj = (size_t)m * NJ + bidx * 64 + e;  // P row-index: [m][j= bidx*64+e]
  float s[8];
#pragma unroll
  for (int u = 0; u < 8; ++u) s[u] = 0.f;
#pragma unroll
  for (int kc = 0; kc < 4; ++kc) {
    short8 v = *(const short8*)(P + (size_t)kc * (NN * NJ) + pj);  // 16B load
#pragma unroll
    for (int u = 0; u < 8; ++u) s[u] += bf2f((unsigned short)v[u]);
  }
  float4 o0 = {s[0], s[1], s[2], s[3]}, o1 = {s[4], s[5], s[6], s[7]};
  ((float4*)(out + of))[0] = o0;
  ((float4*)(out + of))[1] = o1;
}

extern "C" void kernel_launch(void* const* d_in, const int* in_sizes, int n_in,
                              void* d_out, int out_size, void* d_ws, size_t ws_size,
                              hipStream_t stream) {
  const float* Z = (const float*)d_in[0];   // [16][4096][64] fp32
  const float* A = (const float*)d_in[1];   // [4096][4096] fp32
  const float* W = (const float*)d_in[2];   // [64][64] fp32
  float* out = (float*)d_out;               // [16][4096][64] fp32

  unsigned short* Ab = (unsigned short*)d_ws;                                     // 32 MiB bf16 A
  unsigned short* Yt = (unsigned short*)((char*)d_ws + (size_t)32 * 1024 * 1024); // 8 MiB bf16 Y^T
  unsigned short* Pb = (unsigned short*)((char*)d_ws + (size_t)40 * 1024 * 1024); // 32 MiB bf16 partials x4

  k_prep<<<9216, 256, 0, stream>>>(A, Z, W, Ab, Yt);
  k_gemm<<<256, 512, 0, stream>>>(Ab, Yt, Pb);
  k_reduce<<<2048, 256, 0, stream>>>(Pb, out);
}

// Round 6
// 154.789 us; speedup vs baseline: 1.3080x; 1.0040x over previous
//
#include <hip/hip_runtime.h>
#include <hip/hip_bf16.h>
#include <cstdint>

// Problem constants (B=16, N=4096, D_IN=D_OUT=64)
#define NB   16
#define NN   4096
#define ND   64
#define NJ   1024   // NB*ND columns of the big GEMM

typedef __attribute__((ext_vector_type(8))) short  short8;  // 8 bf16 = 4 VGPRs
typedef __attribute__((ext_vector_type(4))) float  f32x4;

__device__ __forceinline__ unsigned short f2bf(float f) {
  union { float f; unsigned int u; } v; v.f = f;
  unsigned int u = v.u;
  unsigned int r = u + 0x7FFFu + ((u >> 16) & 1u);  // round-to-nearest-even
  return (unsigned short)(r >> 16);
}
__device__ __forceinline__ float bf2f(unsigned short h) {
  union { unsigned int u; float f; } v; v.u = ((unsigned int)h) << 16; return v.f;
}

// ---------------- K1: merged prep = {Yt = (Z W)^T} + {A fp32->bf16 convert} --------
// zw blocks FIRST (bx < 1024): latency-bound, hides under the BW-bound convert
// stream (round-5 verified: k_prep 43 -> ~20us, out of top-5).
__global__ void k_prep(const float* __restrict__ A, const float* __restrict__ Z,
                       const float* __restrict__ W, unsigned short* __restrict__ Ab,
                       unsigned short* __restrict__ Yt) {
  __shared__ float zs[64 * 65];                      // 16.25 KiB (zw blocks only)
  int bx = blockIdx.x;
  int tid = threadIdx.x;
  if (bx < 1024) {
    int b  = bx >> 6;                  // [0,16)
    int m0 = (bx & 63) << 6;           // [0,4096) step 64
    // ---- stage Z[b][m0:m0+64][0:64] -> zs, coalesced: 16 thr/row, 4 rounds ----
    const float* zb = Z + ((size_t)b * NN + m0) * ND;
#pragma unroll
    for (int r = 0; r < 4; ++r) {
      int row = r * 16 + (tid >> 4);
      int col = (tid & 15) * 4;
      float4 v = *(const float4*)(zb + (size_t)row * ND + col);
      float* d = &zs[row * 65 + col];
      d[0] = v.x; d[1] = v.y; d[2] = v.z; d[3] = v.w;   // 4x b32: 2 lanes/bank, free
    }
    __syncthreads();
    int lane = tid & 63;                               // = m-row within tile
    int e0 = __builtin_amdgcn_readfirstlane((tid >> 6) << 4);  // wave-uniform -> s_load W
    int m  = m0 + lane;
    float acc[16];
#pragma unroll
    for (int i = 0; i < 16; ++i) acc[i] = 0.f;
#pragma unroll
    for (int d = 0; d < 64; ++d) {
      float zd = zs[lane * 65 + d];                    // bank (lane+d)&31: free
#pragma unroll
      for (int i = 0; i < 16; ++i) acc[i] += zd * W[d * 64 + e0 + i];  // uniform -> SMEM
    }
#pragma unroll
    for (int i = 0; i < 16; ++i)
      Yt[(size_t)(b * 64 + e0 + i) * NN + m] = f2bf(acc[i]);
  } else {
    int idx = (bx - 1024) * 256 + tid;               // 2,097,152 threads exactly
    const float4* p = (const float4*)A + (size_t)idx * 2;
    float4 a = p[0], b = p[1];
    unsigned int w0 = (unsigned int)f2bf(a.x) | ((unsigned int)f2bf(a.y) << 16);
    unsigned int w1 = (unsigned int)f2bf(a.z) | ((unsigned int)f2bf(a.w) << 16);
    unsigned int w2 = (unsigned int)f2bf(b.x) | ((unsigned int)f2bf(b.y) << 16);
    unsigned int w3 = (unsigned int)f2bf(b.z) | ((unsigned int)f2bf(b.w) << 16);
    uint4 o; o.x = w0; o.y = w1; o.z = w2; o.w = w3;
    ((uint4*)Ab)[idx] = o;                           // 16B store
  }
}

// ---------------- K2: 256x256-tile 8-phase GEMM (m201-converged schedule) -----------
// Grid 256 = 16m x 4j x 4kc, 1 block/CU, 512 thr = 8 waves (2M x 4N), per-wave 128x64.
// Round-6 deltas (converge to m201 template exactly):
//  - EVEN stage spread: 2 global_load_lds per phase (ph1 A-h0, ph2 A-h1, ph3 B-h0,
//    ph4 B-h1) instead of the ph1 4-load burst (m196: coarse load placement -7..-27%).
//  - lgkmcnt(8) hint in the 12-ds_read phase before its barrier (m201 template).
// Counted vmcnt(4) once per K-tile unchanged: issue order B(t+1)h0,h1 (t-1 ph3/4),
// A(t+1)h0,h1 (t ph1/2), B(t+2)h0,h1 (t ph3/4) -> oldest 8 = tile t+1 complete.
__device__ __forceinline__ void gl2lds16(const unsigned short* g, unsigned short* l) {
  __builtin_amdgcn_global_load_lds(
      (const __attribute__((address_space(1))) unsigned int*)g,
      (__attribute__((address_space(3))) unsigned int*)l, 16, 0, 0);
}

#define STAGE2(GP, LP, H) \
  gl2lds16((GP) + sOff[H][0], (LP) + dBase[H][0]); \
  gl2lds16((GP) + sOff[H][1], (LP) + dBase[H][1]);

#define READ_A(I0) \
  afr[0][0] = *(const short8*)&lt[aBase + (I0) * 1024 + c0]; \
  afr[0][1] = *(const short8*)&lt[aBase + (I0) * 1024 + c1]; \
  afr[1][0] = *(const short8*)&lt[aBase + ((I0) + 1) * 1024 + c0]; \
  afr[1][1] = *(const short8*)&lt[aBase + ((I0) + 1) * 1024 + c1];

#define MFMA_Q(I0) \
  _Pragma("unroll") \
  for (int jj = 0; jj < 4; ++jj) { \
    acc[(I0)][jj]     = __builtin_amdgcn_mfma_f32_16x16x32_bf16(afr[0][0], bfr[jj][0], acc[(I0)][jj], 0, 0, 0); \
    acc[(I0)][jj]     = __builtin_amdgcn_mfma_f32_16x16x32_bf16(afr[0][1], bfr[jj][1], acc[(I0)][jj], 0, 0, 0); \
    acc[(I0) + 1][jj] = __builtin_amdgcn_mfma_f32_16x16x32_bf16(afr[1][0], bfr[jj][0], acc[(I0) + 1][jj], 0, 0, 0); \
    acc[(I0) + 1][jj] = __builtin_amdgcn_mfma_f32_16x16x32_bf16(afr[1][1], bfr[jj][1], acc[(I0) + 1][jj], 0, 0, 0); \
  }

#define PHASE_MFMA(I0) \
  __builtin_amdgcn_s_barrier(); \
  asm volatile("" ::: "memory"); /* compiler fence; HW waits are data-dep lgkmcnt(N) */ \
  __builtin_amdgcn_s_setprio(1); \
  MFMA_Q(I0) \
  __builtin_amdgcn_s_setprio(0); \
  __builtin_amdgcn_s_barrier();

__launch_bounds__(512, 2)  // 8 waves, 1 block/CU (128 KiB LDS), VGPR cap 256
__global__ void k_gemm(const unsigned short* __restrict__ Ab,
                       const unsigned short* __restrict__ Yt,
                       unsigned short* __restrict__ Pb) {
  __shared__ unsigned short lds[65536];  // 128 KiB
  const int tid = threadIdx.x;
  const int w = tid >> 6, lane = tid & 63;
  const int quad = lane >> 4, l15 = lane & 15;
  const int wr = w >> 2, wc = w & 3;

  const int m_blk = blockIdx.x & 15;         // XCD = bx%8 = m_blk&7: 4 j_blks share
  const int j_blk = (blockIdx.x >> 4) & 3;   // one A strip per XCD L2
  const int kc    = blockIdx.x >> 6;
  const int mrow0 = m_blk << 8, jcol0 = j_blk << 8, kbase = kc << 10;

  const unsigned short* Ag = Ab + (size_t)mrow0 * 4096 + kbase;
  const unsigned short* Bg = Yt + (size_t)jcol0 * 4096 + kbase;

  // Staging offsets: half h, round r -> uniform LDS slot base h*1024+r*512+w*64,
  // per-lane slot s = base+lane, global source (row=s>>3, kg=(s&7)^(row&7)).
  int sOff[2][2], dBase[2][2];
#pragma unroll
  for (int h = 0; h < 2; ++h)
#pragma unroll
    for (int r = 0; r < 2; ++r) {
      int s = h * 1024 + r * 512 + w * 64 + lane;
      int row = s >> 3;
      int kg = (s & 7) ^ (row & 7);
      sOff[h][r]  = row * 4096 + kg * 8;
      dBase[h][r] = (h * 1024 + r * 512 + w * 64) * 8;  // wave-uniform (shorts)
    }

  // ds_read chunk offsets (shorts): row&7 == l15&7 for all fragment rows.
  const int c0 = (quad ^ (l15 & 7)) * 8;
  const int c1 = ((4 + quad) ^ (l15 & 7)) * 8;
  const int aBase = (wr * 128 + l15) * 64;            // + i*1024 + c{0,1}
  const int bBase = 32768 + (wc * 64 + l15) * 64;     // + j*1024 + c{0,1} (rel. lds+p*16384)

  f32x4 acc[8][4];
#pragma unroll
  for (int i = 0; i < 8; ++i)
#pragma unroll
    for (int j = 0; j < 4; ++j) acc[i][j] = (f32x4){0.f, 0.f, 0.f, 0.f};

  // Prologue: tile0 A+B -> buf0 (8 loads), tile1 B -> buf1 (4 loads).
  // vmcnt(4): tile0 (oldest 8) landed, tile1-B still in flight.
  STAGE2(Ag, lds, 0) STAGE2(Ag, lds, 1)
  STAGE2(Bg, lds + 32768, 0) STAGE2(Bg, lds + 32768, 1)
  STAGE2(Bg + 64, lds + 49152, 0) STAGE2(Bg + 64, lds + 49152, 1)
  asm volatile("s_waitcnt vmcnt(4)" ::: "memory");
  __builtin_amdgcn_s_barrier();

  for (int t = 0; t < 16; ++t) {
    const int p = t & 1;
    const unsigned short* lt = lds + p * 16384;
    short8 bfr[4][2], afr[2][2];

    // ---- phase 1: all B-frags + A-quad0; stage A(t+1) half 0; lgkm(8) hint ----
#pragma unroll
    for (int j = 0; j < 4; ++j) {
      bfr[j][0] = *(const short8*)&lt[bBase + j * 1024 + c0];
      bfr[j][1] = *(const short8*)&lt[bBase + j * 1024 + c1];
    }
    READ_A(0)
    if (t < 15) {
      const unsigned short* g = Ag + (t + 1) * 64;
      unsigned short* lb = lds + (p ^ 1) * 16384;
      STAGE2(g, lb, 0)
    }
    asm volatile("s_waitcnt lgkmcnt(8)" ::: "memory");  // 12 ds_reads this phase
    PHASE_MFMA(0)

    // ---- phase 2: A-quad1; stage A(t+1) half 1 ----
    READ_A(2)
    if (t < 15) {
      const unsigned short* g = Ag + (t + 1) * 64;
      unsigned short* lb = lds + (p ^ 1) * 16384;
      STAGE2(g, lb, 1)
    }
    PHASE_MFMA(2)

    // ---- phase 3: A-quad2; stage B(t+2) half 0 (tile-t B region read in ph1) ----
    READ_A(4)
    if (t < 14) {
      const unsigned short* g = Bg + (t + 2) * 64;
      unsigned short* lb = lds + 32768 + p * 16384;
      STAGE2(g, lb, 0)
    }
    PHASE_MFMA(4)

    // ---- phase 4: A-quad3; stage B(t+2) half 1; counted vmcnt once per K-tile ----
    READ_A(6)
    if (t < 14) {
      const unsigned short* g = Bg + (t + 2) * 64;
      unsigned short* lb = lds + 32768 + p * 16384;
      STAGE2(g, lb, 1)
    }
    if (t < 14) { asm volatile("s_waitcnt vmcnt(4)" ::: "memory"); }
    else if (t == 14) { asm volatile("s_waitcnt vmcnt(0)" ::: "memory"); }
    PHASE_MFMA(6)
  }

  // Epilogue: C/D layout col=l15, row=quad*4+reg (m89/m91-verified mapping).
  unsigned short* P = Pb + (size_t)kc * ((size_t)NN * NJ);
  const int r0base = mrow0 + wr * 128;
  const int cb = jcol0 + wc * 64;
#pragma unroll
  for (int i = 0; i < 8; ++i) {
    const int r0 = r0base + i * 16 + quad * 4;
#pragma unroll
    for (int j = 0; j < 4; ++j) {
      const int jc = cb + j * 16 + l15;
      unsigned short* pp = P + (size_t)r0 * NJ + jc;
#pragma unroll
      for (int rg = 0; rg < 4; ++rg)
        pp[(size_t)rg * NJ] = f2bf(acc[i][j][rg]);
    }
  }
}

// ---------------- K3: out[m-major] = sum_kc P[kc]; 8 floats/thread ------------------
__global__ void k_reduce(const unsigned short* __restrict__ P, float* __restrict__ out) {
  int t = blockIdx.x * 256 + threadIdx.x;      // 524,288 threads exactly
  size_t of = (size_t)t * 8;                   // out flat index (8 consecutive floats)
  int bidx = t >> 15;                          // of >> 18
  int rem  = (int)(of & 262143);               // within one batch: m*64 + e
  int m = rem >> 6, e = rem & 63;
  size_t pj = (size_t)m * NJ + bidx * 64 + e;  // P row-index: [m][j= bidx*64+e]
  float s[8];
#pragma unroll
  for (int u = 0; u < 8; ++u) s[u] = 0.f;
#pragma unroll
  for (int kc = 0; kc < 4; ++kc) {
    short8 v = *(const short8*)(P + (size_t)kc * (NN * NJ) + pj);  // 16B load
#pragma unroll
    for (int u = 0; u < 8; ++u) s[u] += bf2f((unsigned short)v[u]);
  }
  float4 o0 = {s[0], s[1], s[2], s[3]}, o1 = {s[4], s[5], s[6], s[7]};
  ((float4*)(out + of))[0] = o0;
  ((float4*)(out + of))[1] = o1;
}

extern "C" void kernel_launch(void* const* d_in, const int* in_sizes, int n_in,
                              void* d_out, int out_size, void* d_ws, size_t ws_size,
                              hipStream_t stream) {
  const float* Z = (const float*)d_in[0];   // [16][4096][64] fp32
  const float* A = (const float*)d_in[1];   // [4096][4096] fp32
  const float* W = (const float*)d_in[2];   // [64][64] fp32
  float* out = (float*)d_out;               // [16][4096][64] fp32

  unsigned short* Ab = (unsigned short*)d_ws;                                     // 32 MiB bf16 A
  unsigned short* Yt = (unsigned short*)((char*)d_ws + (size_t)32 * 1024 * 1024); // 8 MiB bf16 Y^T
  unsigned short* Pb = (unsigned short*)((char*)d_ws + (size_t)40 * 1024 * 1024); // 32 MiB bf16 partials x4

  k_prep<<<9216, 256, 0, stream>>>(A, Z, W, Ab, Yt);
  k_gemm<<<256, 512, 0, stream>>>(Ab, Yt, Pb);
  k_reduce<<<2048, 256, 0, stream>>>(Pb, out);
}